// Round 6
// baseline (843.687 us; speedup 1.0000x reference)
//
#include <hip/hip_runtime.h>

typedef unsigned int   uint;
typedef unsigned short ushort;
typedef __attribute__((ext_vector_type(8))) short bf16x8;   // 8 bf16 (4 VGPRs)
typedef __attribute__((ext_vector_type(4))) float f32x4;

#define N_NODES 50000
#define N_EDGES 800000
#define IN_F    512
#define OUT_F   96
#define SCAN_BLOCKS 196   // 196*256 >= 50000
#define TPN 12            // threads per node in prop (96 feats / 8 per lane)
#define NBINS 64

// bf16 helpers (storage-only bf16; math in fp32)
__device__ __forceinline__ float bflo(uint u) { return __uint_as_float(u << 16); }
__device__ __forceinline__ float bfhi(uint u) { return __uint_as_float(u & 0xffff0000u); }
__device__ __forceinline__ uint f2bf(float x) {          // round-to-nearest-even
    uint u = __float_as_uint(x);
    return (u + 0x7fffu + ((u >> 16) & 1u)) >> 16;
}
__device__ __forceinline__ uint pack2bf(float lo, float hi) {
    return f2bf(lo) | (f2bf(hi) << 16);
}

// ---------------------------------------------------------------------------
// w[512,96] fp32 -> wT[96,512] bf16
// ---------------------------------------------------------------------------
__global__ __launch_bounds__(256) void wt_kernel(const float* __restrict__ w,
                                                 ushort* __restrict__ wT) {
    int t = blockIdx.x * 256 + threadIdx.x;
    if (t < IN_F * OUT_F) {
        int k = t / OUT_F, c = t - k * OUT_F;
        wT[(size_t)c * IN_F + k] = (ushort)f2bf(w[t]);
    }
}

// ---------------------------------------------------------------------------
// MFMA GEMM, software-pipelined: supB[N,96](bf16) = x[N,512] @ w[512,96]
// Wave: 16 rows x 96 cols, 6x mfma_16x16x32_bf16 per 32-K chunk, 16 chunks.
// Next chunk's x (2x16B) and wT (6x16B) loads issue before current compute.
// ---------------------------------------------------------------------------
__global__ __launch_bounds__(256) void gemm_kernel(const float* __restrict__ x,
                                                   const ushort* __restrict__ wT,
                                                   ushort* __restrict__ supB) {
    const int tid  = threadIdx.x;
    const int wv   = tid >> 6;
    const int lane = tid & 63;
    const int m    = lane & 15;
    const int quad = lane >> 4;

    const int row  = blockIdx.x * 64 + wv * 16 + m;
    const int arow = (row < N_NODES) ? row : (N_NODES - 1);
    const float*  xp = x  + (size_t)arow * IN_F + quad * 8;
    const ushort* wp = wT + (size_t)m * IN_F + quad * 8;

    f32x4 acc[6];
    #pragma unroll
    for (int ct = 0; ct < 6; ++ct) acc[ct] = (f32x4){0.f, 0.f, 0.f, 0.f};

    // prologue: chunk 0 in flight
    float4 xa = *(const float4*)(xp);
    float4 xb = *(const float4*)(xp + 4);
    bf16x8 b[6];
    #pragma unroll
    for (int ct = 0; ct < 6; ++ct)
        b[ct] = *(const bf16x8*)(wp + (size_t)ct * 16 * IN_F);

    #pragma unroll
    for (int it = 0; it < 15; ++it) {
        const int kn = (it + 1) * 32;
        // prefetch next chunk
        float4 xa2 = *(const float4*)(xp + kn);
        float4 xb2 = *(const float4*)(xp + kn + 4);
        bf16x8 b2[6];
        #pragma unroll
        for (int ct = 0; ct < 6; ++ct)
            b2[ct] = *(const bf16x8*)(wp + (size_t)ct * 16 * IN_F + kn);
        // compute current
        union { uint u[4]; bf16x8 v; } af;
        af.u[0] = pack2bf(xa.x, xa.y); af.u[1] = pack2bf(xa.z, xa.w);
        af.u[2] = pack2bf(xb.x, xb.y); af.u[3] = pack2bf(xb.z, xb.w);
        #pragma unroll
        for (int ct = 0; ct < 6; ++ct)
            acc[ct] = __builtin_amdgcn_mfma_f32_16x16x32_bf16(af.v, b[ct],
                                                              acc[ct], 0, 0, 0);
        xa = xa2; xb = xb2;
        #pragma unroll
        for (int ct = 0; ct < 6; ++ct) b[ct] = b2[ct];
    }
    { // epilogue chunk
        union { uint u[4]; bf16x8 v; } af;
        af.u[0] = pack2bf(xa.x, xa.y); af.u[1] = pack2bf(xa.z, xa.w);
        af.u[2] = pack2bf(xb.x, xb.y); af.u[3] = pack2bf(xb.z, xb.w);
        #pragma unroll
        for (int ct = 0; ct < 6; ++ct)
            acc[ct] = __builtin_amdgcn_mfma_f32_16x16x32_bf16(af.v, b[ct],
                                                              acc[ct], 0, 0, 0);
    }

    // C/D layout: col = lane&15 (=m), row = quad*4 + reg
    const int orow0 = blockIdx.x * 64 + wv * 16 + quad * 4;
    #pragma unroll
    for (int ct = 0; ct < 6; ++ct) {
        #pragma unroll
        for (int r = 0; r < 4; ++r) {
            int gr = orow0 + r;
            if (gr < N_NODES)
                supB[(size_t)gr * OUT_F + ct * 16 + m] = (ushort)f2bf(acc[ct][r]);
        }
    }
}

// ---------------------------------------------------------------------------
// CSR build with degree-sorted renumbering.
// ---------------------------------------------------------------------------
__global__ void zero_kernel(int* __restrict__ p, int n) {
    int t = blockIdx.x * blockDim.x + threadIdx.x;
    if (t < n) p[t] = 0;
}

__global__ void hist_kernel(const int* __restrict__ dst, int* __restrict__ counts) {
    int e = blockIdx.x * blockDim.x + threadIdx.x;
    if (e < N_EDGES) atomicAdd(&counts[dst[e]], 1);
}

// 64-bin degree histogram
__global__ void degbin_kernel(const int* __restrict__ counts, int* __restrict__ bins) {
    int n = blockIdx.x * blockDim.x + threadIdx.x;
    if (n < N_NODES) {
        int b = counts[n]; if (b > NBINS - 1) b = NBINS - 1;
        atomicAdd(&bins[b], 1);
    }
}

// exclusive scan of 64 bins (single wave) -> binCur
__global__ __launch_bounds__(64) void binscan_kernel(const int* __restrict__ bins,
                                                     int* __restrict__ binCur) {
    __shared__ int s[NBINS];
    int t = threadIdx.x;
    s[t] = bins[t];
    __syncthreads();
    for (int off = 1; off < NBINS; off <<= 1) {
        int v = (t >= off) ? s[t - off] : 0;
        __syncthreads();
        s[t] += v;
        __syncthreads();
    }
    binCur[t] = s[t] - bins[t];   // exclusive
}

// counting-sort nodes by degree -> perm / invperm
__global__ void permscatter_kernel(const int* __restrict__ counts,
                                   int* __restrict__ binCur,
                                   int* __restrict__ perm,
                                   int* __restrict__ invperm) {
    int n = blockIdx.x * blockDim.x + threadIdx.x;
    if (n < N_NODES) {
        int b = counts[n]; if (b > NBINS - 1) b = NBINS - 1;
        int pos = atomicAdd(&binCur[b], 1);
        perm[pos]  = n;
        invperm[n] = pos;
    }
}

__global__ __launch_bounds__(256) void block_reduce_kernel(const int* __restrict__ counts,
                                                           const int* __restrict__ perm,
                                                           int* __restrict__ blockSums) {
    __shared__ int s[256];
    int idx = blockIdx.x * 256 + threadIdx.x;
    s[threadIdx.x] = (idx < N_NODES) ? counts[perm[idx]] : 0;
    __syncthreads();
    for (int off = 128; off > 0; off >>= 1) {
        if (threadIdx.x < off) s[threadIdx.x] += s[threadIdx.x + off];
        __syncthreads();
    }
    if (threadIdx.x == 0) blockSums[blockIdx.x] = s[0];
}

__global__ __launch_bounds__(256) void scan_sums_kernel(int* __restrict__ blockSums,
                                                        int* __restrict__ blockOffs,
                                                        int* __restrict__ rowstart) {
    __shared__ int s[256];
    int t = threadIdx.x;
    s[t] = (t < SCAN_BLOCKS) ? blockSums[t] : 0;
    __syncthreads();
    for (int off = 1; off < 256; off <<= 1) {
        int v = (t >= off) ? s[t - off] : 0;
        __syncthreads();
        s[t] += v;
        __syncthreads();
    }
    if (t < SCAN_BLOCKS) blockOffs[t] = (t == 0) ? 0 : s[t - 1];
    if (t == 0) rowstart[N_NODES] = s[SCAN_BLOCKS - 1];
}

__global__ __launch_bounds__(256) void block_scan_kernel(const int* __restrict__ counts,
                                                         const int* __restrict__ perm,
                                                         const int* __restrict__ blockOffs,
                                                         int* __restrict__ rowstart,
                                                         int* __restrict__ cursor) {
    __shared__ int s[256];
    int t   = threadIdx.x;
    int idx = blockIdx.x * 256 + t;
    int v   = (idx < N_NODES) ? counts[perm[idx]] : 0;
    s[t] = v;
    __syncthreads();
    for (int off = 1; off < 256; off <<= 1) {
        int u = (t >= off) ? s[t - off] : 0;
        __syncthreads();
        s[t] += u;
        __syncthreads();
    }
    if (idx < N_NODES) {
        int excl = blockOffs[blockIdx.x] + s[t] - v;
        rowstart[idx] = excl;
        cursor[idx]   = excl;
    }
}

// edges into renumbered CSR; src also renumbered
__global__ void scatter_kernel(const int* __restrict__ src, const int* __restrict__ dst,
                               const float* __restrict__ val,
                               const int* __restrict__ invperm,
                               int* __restrict__ cursor, int2* __restrict__ edgeP) {
    int e = blockIdx.x * blockDim.x + threadIdx.x;
    if (e < N_EDGES) {
        int dnew = invperm[dst[e]];
        int pos  = atomicAdd(&cursor[dnew], 1);
        edgeP[pos] = make_int2(invperm[src[e]], __float_as_int(val[e]));
    }
}

// supP[j,:] = supB[perm[j],:]   (16B segments, coalesced store)
__global__ void permsup_kernel(const ushort* __restrict__ supB,
                               const int* __restrict__ perm,
                               ushort* __restrict__ supP) {
    int t = blockIdx.x * blockDim.x + threadIdx.x;   // 600000 threads
    int j = t / TPN;
    if (j >= N_NODES) return;
    int q = t - j * TPN;
    *(uint4*)(supP + (size_t)j * OUT_F + q * 8) =
        *(const uint4*)(supB + (size_t)perm[j] * OUT_F + q * 8);
}

// ---------------------------------------------------------------------------
// Propagation (renumbered order). 8-edge unroll. FINAL writes fp32 at the
// ORIGINAL node index perm[j].
// ---------------------------------------------------------------------------
__device__ __forceinline__ void acc8(float* a, float v, uint4 hv) {
    a[0] = fmaf(v, bflo(hv.x), a[0]); a[1] = fmaf(v, bfhi(hv.x), a[1]);
    a[2] = fmaf(v, bflo(hv.y), a[2]); a[3] = fmaf(v, bfhi(hv.y), a[3]);
    a[4] = fmaf(v, bflo(hv.z), a[4]); a[5] = fmaf(v, bfhi(hv.z), a[5]);
    a[6] = fmaf(v, bflo(hv.w), a[6]); a[7] = fmaf(v, bfhi(hv.w), a[7]);
}

template <bool FINAL>
__global__ __launch_bounds__(256) void prop_kernel(const ushort* __restrict__ h,
                                                   const ushort* __restrict__ sup,
                                                   const int* __restrict__ rowstart,
                                                   const int2* __restrict__ edgeP,
                                                   const int* __restrict__ perm,
                                                   ushort* __restrict__ outB,
                                                   float* __restrict__ outF) {
    int t = blockIdx.x * 256 + threadIdx.x;
    int i = t / TPN;
    if (i >= N_NODES) return;
    int q = t - i * TPN;
    int f = q * 8;

    int start = rowstart[i];
    int end   = rowstart[i + 1];

    float a[8] = {0.f, 0.f, 0.f, 0.f, 0.f, 0.f, 0.f, 0.f};
    int e = start;
    for (; e + 7 < end; e += 8) {
        int2 ed[8];
        #pragma unroll
        for (int u = 0; u < 8; ++u) ed[u] = edgeP[e + u];
        uint4 hv[8];
        #pragma unroll
        for (int u = 0; u < 8; ++u)
            hv[u] = *(const uint4*)(h + (size_t)ed[u].x * OUT_F + f);
        #pragma unroll
        for (int u = 0; u < 8; ++u) acc8(a, __int_as_float(ed[u].y), hv[u]);
    }
    for (; e < end; ++e) {
        int2 e0 = edgeP[e];
        uint4 h0 = *(const uint4*)(h + (size_t)e0.x * OUT_F + f);
        acc8(a, __int_as_float(e0.y), h0);
    }

    size_t o = (size_t)i * OUT_F + f;
    uint4 sp = *(const uint4*)(sup + o);
    float r[8];
    r[0] = fmaxf(fmaf(a[0], 0.9f, bflo(sp.x) * 0.1f), 0.f);
    r[1] = fmaxf(fmaf(a[1], 0.9f, bfhi(sp.x) * 0.1f), 0.f);
    r[2] = fmaxf(fmaf(a[2], 0.9f, bflo(sp.y) * 0.1f), 0.f);
    r[3] = fmaxf(fmaf(a[3], 0.9f, bfhi(sp.y) * 0.1f), 0.f);
    r[4] = fmaxf(fmaf(a[4], 0.9f, bflo(sp.z) * 0.1f), 0.f);
    r[5] = fmaxf(fmaf(a[5], 0.9f, bfhi(sp.z) * 0.1f), 0.f);
    r[6] = fmaxf(fmaf(a[6], 0.9f, bflo(sp.w) * 0.1f), 0.f);
    r[7] = fmaxf(fmaf(a[7], 0.9f, bfhi(sp.w) * 0.1f), 0.f);

    if (FINAL) {
        size_t oo = (size_t)perm[i] * OUT_F + f;
        *(float4*)(outF + oo)     = make_float4(r[0], r[1], r[2], r[3]);
        *(float4*)(outF + oo + 4) = make_float4(r[4], r[5], r[6], r[7]);
    } else {
        *(uint4*)(outB + o) = make_uint4(pack2bf(r[0], r[1]), pack2bf(r[2], r[3]),
                                         pack2bf(r[4], r[5]), pack2bf(r[6], r[7]));
    }
}

// ---------------------------------------------------------------------------
// Buffers: d_out low 9.6MB = supB (gemm out), top 98KB = wT; final prop
// overwrites d_out fully (supB/wT dead by then — props use supP copy).
// d_in[0] (x, 102.4MB) = scratch AFTER gemm (sole reader of x). d_ws unused.
// ---------------------------------------------------------------------------
extern "C" void kernel_launch(void* const* d_in, const int* in_sizes, int n_in,
                              void* d_out, int out_size, void* d_ws, size_t ws_size,
                              hipStream_t stream) {
    const float* x    = (const float*)d_in[0];
    const float* w    = (const float*)d_in[1];
    const int*   esrc = (const int*)d_in[2];
    const int*   edst = (const int*)d_in[3];
    const float* eval = (const float*)d_in[4];
    float* out = (float*)d_out;

    const size_t supBytes = (size_t)N_NODES * OUT_F * sizeof(ushort);  // 9.6MB
    ushort* supB = (ushort*)d_out;
    ushort* wTb  = (ushort*)((char*)d_out + (size_t)out_size * 4
                             - (size_t)IN_F * OUT_F * sizeof(ushort));

    char*  xb  = (char*)d_in[0];
    size_t off = 0;
    auto alloc = [&](size_t bytes) -> char* {
        char* p = xb + off;
        off = (off + bytes + 255) & ~(size_t)255;
        return p;
    };
    ushort* supP      = (ushort*)alloc(supBytes);
    ushort* hU        = (ushort*)alloc(supBytes);
    ushort* hV        = (ushort*)alloc(supBytes);
    int2*   edgeP     = (int2*)alloc((size_t)N_EDGES * sizeof(int2));
    int*    rowstart  = (int*)alloc((N_NODES + 1) * sizeof(int));
    int*    cursor    = (int*)alloc(N_NODES * sizeof(int));
    int*    counts    = (int*)alloc(N_NODES * sizeof(int));
    int*    perm      = (int*)alloc(N_NODES * sizeof(int));
    int*    invperm   = (int*)alloc(N_NODES * sizeof(int));
    int*    binsAll   = (int*)alloc(2 * NBINS * sizeof(int));  // bins | binCur
    int*    blockSums = (int*)alloc(SCAN_BLOCKS * sizeof(int));
    int*    blockOffs = (int*)alloc(SCAN_BLOCKS * sizeof(int));
    int* bins   = binsAll;
    int* binCur = binsAll + NBINS;

    // 1) weights -> bf16 transposed (d_out top)
    wt_kernel<<<(IN_F * OUT_F + 255) / 256, 256, 0, stream>>>(w, wTb);

    // 2) MFMA GEMM (last reader of x) -> supB in d_out
    gemm_kernel<<<(N_NODES + 63) / 64, 256, 0, stream>>>(x, wTb, supB);

    // 3) CSR build + degree sort (x-scratch; safe post-gemm in stream order)
    zero_kernel<<<(N_NODES + 255) / 256, 256, 0, stream>>>(counts, N_NODES);
    zero_kernel<<<1, 2 * NBINS, 0, stream>>>(binsAll, 2 * NBINS);
    hist_kernel<<<(N_EDGES + 255) / 256, 256, 0, stream>>>(edst, counts);
    degbin_kernel<<<(N_NODES + 255) / 256, 256, 0, stream>>>(counts, bins);
    binscan_kernel<<<1, NBINS, 0, stream>>>(bins, binCur);
    permscatter_kernel<<<(N_NODES + 255) / 256, 256, 0, stream>>>(counts, binCur,
                                                                  perm, invperm);
    block_reduce_kernel<<<SCAN_BLOCKS, 256, 0, stream>>>(counts, perm, blockSums);
    scan_sums_kernel<<<1, 256, 0, stream>>>(blockSums, blockOffs, rowstart);
    block_scan_kernel<<<SCAN_BLOCKS, 256, 0, stream>>>(counts, perm, blockOffs,
                                                       rowstart, cursor);
    scatter_kernel<<<(N_EDGES + 255) / 256, 256, 0, stream>>>(esrc, edst, eval,
                                                              invperm, cursor, edgeP);
    permsup_kernel<<<(N_NODES * TPN + 255) / 256, 256, 0, stream>>>(supB, perm, supP);

    // 4) 10 propagation iterations: supP -> hU -> hV -> ... -> d_out (fp32)
    const int pgrid = (N_NODES * TPN + 255) / 256;
    const ushort* in = supP;
    for (int it = 1; it <= 9; ++it) {
        ushort* o = (it & 1) ? hU : hV;
        prop_kernel<false><<<pgrid, 256, 0, stream>>>(in, supP, rowstart, edgeP,
                                                      perm, o, nullptr);
        in = o;
    }
    prop_kernel<true><<<pgrid, 256, 0, stream>>>(in, supP, rowstart, edgeP,
                                                 perm, nullptr, out);
}

// Round 7
// 569.337 us; speedup vs baseline: 1.4819x; 1.4819x over previous
//
#include <hip/hip_runtime.h>

typedef unsigned int   uint;
typedef unsigned short ushort;
typedef __attribute__((ext_vector_type(8))) short bf16x8;   // 8 bf16 (4 VGPRs)
typedef __attribute__((ext_vector_type(4))) float f32x4;

#define N_NODES 50000
#define N_EDGES 800000
#define IN_F    512
#define OUT_F   96
#define SCAN_BLOCKS 196   // 196*256 >= 50000
#define TPN 12            // threads per node in prop (96 feats / 8 per lane)

// bf16 helpers (storage-only bf16; math in fp32)
__device__ __forceinline__ float bflo(uint u) { return __uint_as_float(u << 16); }
__device__ __forceinline__ float bfhi(uint u) { return __uint_as_float(u & 0xffff0000u); }
__device__ __forceinline__ uint f2bf(float x) {          // round-to-nearest-even
    uint u = __float_as_uint(x);
    return (u + 0x7fffu + ((u >> 16) & 1u)) >> 16;
}
__device__ __forceinline__ uint pack2bf(float lo, float hi) {
    return f2bf(lo) | (f2bf(hi) << 16);
}

// ---------------------------------------------------------------------------
// w[512,96] fp32 -> wTp chunk-major bf16: wTp[k/32][c][k%32].
// One GEMM B-frag instruction then reads 64 lanes x 16B = 1KB contiguous.
// ---------------------------------------------------------------------------
__global__ __launch_bounds__(256) void wt_kernel(const float* __restrict__ w,
                                                 ushort* __restrict__ wTp) {
    int t = blockIdx.x * 256 + threadIdx.x;
    if (t < IN_F * OUT_F) {
        int k = t / OUT_F, c = t - k * OUT_F;
        wTp[(size_t)(k >> 5) * (OUT_F * 32) + c * 32 + (k & 31)] =
            (ushort)f2bf(w[t]);
    }
}

// ---------------------------------------------------------------------------
// MFMA GEMM, software-pipelined: supB[N,96](bf16) = x[N,512] @ w[512,96]
// Wave: 16 rows x 96 cols, 6x mfma_16x16x32_bf16 per 32-K chunk, 16 chunks.
// B-frags from chunk-major wTp: each load fully coalesced (1KB/wave-instr).
// ---------------------------------------------------------------------------
__global__ __launch_bounds__(256) void gemm_kernel(const float* __restrict__ x,
                                                   const ushort* __restrict__ wTp,
                                                   ushort* __restrict__ supB) {
    const int tid  = threadIdx.x;
    const int wv   = tid >> 6;
    const int lane = tid & 63;
    const int m    = lane & 15;
    const int quad = lane >> 4;

    const int row  = blockIdx.x * 64 + wv * 16 + m;
    const int arow = (row < N_NODES) ? row : (N_NODES - 1);
    const float*  xp = x + (size_t)arow * IN_F + quad * 8;
    // per-lane base into chunk-major wTp (chunk 0): col = ct*16+m, k-seg quad*8
    const ushort* wp = wTp + (size_t)m * 32 + quad * 8;

    f32x4 acc[6];
    #pragma unroll
    for (int ct = 0; ct < 6; ++ct) acc[ct] = (f32x4){0.f, 0.f, 0.f, 0.f};

    // prologue: chunk 0 in flight
    float4 xa = *(const float4*)(xp);
    float4 xb = *(const float4*)(xp + 4);
    bf16x8 b[6];
    #pragma unroll
    for (int ct = 0; ct < 6; ++ct)
        b[ct] = *(const bf16x8*)(wp + ct * (16 * 32));

    #pragma unroll
    for (int it = 0; it < 15; ++it) {
        // prefetch next chunk
        const int kn = (it + 1) * 32;
        float4 xa2 = *(const float4*)(xp + kn);
        float4 xb2 = *(const float4*)(xp + kn + 4);
        bf16x8 b2[6];
        const ushort* wpn = wp + (size_t)(it + 1) * (OUT_F * 32);
        #pragma unroll
        for (int ct = 0; ct < 6; ++ct)
            b2[ct] = *(const bf16x8*)(wpn + ct * (16 * 32));
        // compute current
        union { uint u[4]; bf16x8 v; } af;
        af.u[0] = pack2bf(xa.x, xa.y); af.u[1] = pack2bf(xa.z, xa.w);
        af.u[2] = pack2bf(xb.x, xb.y); af.u[3] = pack2bf(xb.z, xb.w);
        #pragma unroll
        for (int ct = 0; ct < 6; ++ct)
            acc[ct] = __builtin_amdgcn_mfma_f32_16x16x32_bf16(af.v, b[ct],
                                                              acc[ct], 0, 0, 0);
        xa = xa2; xb = xb2;
        #pragma unroll
        for (int ct = 0; ct < 6; ++ct) b[ct] = b2[ct];
    }
    { // epilogue chunk
        union { uint u[4]; bf16x8 v; } af;
        af.u[0] = pack2bf(xa.x, xa.y); af.u[1] = pack2bf(xa.z, xa.w);
        af.u[2] = pack2bf(xb.x, xb.y); af.u[3] = pack2bf(xb.z, xb.w);
        #pragma unroll
        for (int ct = 0; ct < 6; ++ct)
            acc[ct] = __builtin_amdgcn_mfma_f32_16x16x32_bf16(af.v, b[ct],
                                                              acc[ct], 0, 0, 0);
    }

    // C/D layout: col = lane&15 (=m), row = quad*4 + reg
    const int orow0 = blockIdx.x * 64 + wv * 16 + quad * 4;
    #pragma unroll
    for (int ct = 0; ct < 6; ++ct) {
        #pragma unroll
        for (int r = 0; r < 4; ++r) {
            int gr = orow0 + r;
            if (gr < N_NODES)
                supB[(size_t)gr * OUT_F + ct * 16 + m] = (ushort)f2bf(acc[ct][r]);
        }
    }
}

// ---------------------------------------------------------------------------
// CSR build: histogram -> hierarchical scan -> scatter (packed int2 edges)
// ---------------------------------------------------------------------------
__global__ void zero_kernel(int* __restrict__ p, int n) {
    int t = blockIdx.x * blockDim.x + threadIdx.x;
    if (t < n) p[t] = 0;
}

__global__ void hist_kernel(const int* __restrict__ dst, int* __restrict__ counts) {
    int e = blockIdx.x * blockDim.x + threadIdx.x;
    if (e < N_EDGES) atomicAdd(&counts[dst[e]], 1);
}

__global__ __launch_bounds__(256) void block_reduce_kernel(const int* __restrict__ counts,
                                                           int* __restrict__ blockSums) {
    __shared__ int s[256];
    int idx = blockIdx.x * 256 + threadIdx.x;
    s[threadIdx.x] = (idx < N_NODES) ? counts[idx] : 0;
    __syncthreads();
    for (int off = 128; off > 0; off >>= 1) {
        if (threadIdx.x < off) s[threadIdx.x] += s[threadIdx.x + off];
        __syncthreads();
    }
    if (threadIdx.x == 0) blockSums[blockIdx.x] = s[0];
}

__global__ __launch_bounds__(256) void scan_sums_kernel(int* __restrict__ blockSums,
                                                        int* __restrict__ blockOffs,
                                                        int* __restrict__ rowstart) {
    __shared__ int s[256];
    int t = threadIdx.x;
    s[t] = (t < SCAN_BLOCKS) ? blockSums[t] : 0;
    __syncthreads();
    for (int off = 1; off < 256; off <<= 1) {
        int v = (t >= off) ? s[t - off] : 0;
        __syncthreads();
        s[t] += v;
        __syncthreads();
    }
    if (t < SCAN_BLOCKS) blockOffs[t] = (t == 0) ? 0 : s[t - 1];
    if (t == 0) rowstart[N_NODES] = s[SCAN_BLOCKS - 1];
}

__global__ __launch_bounds__(256) void block_scan_kernel(const int* __restrict__ counts,
                                                         const int* __restrict__ blockOffs,
                                                         int* __restrict__ rowstart,
                                                         int* __restrict__ cursor) {
    __shared__ int s[256];
    int t   = threadIdx.x;
    int idx = blockIdx.x * 256 + t;
    int v   = (idx < N_NODES) ? counts[idx] : 0;
    s[t] = v;
    __syncthreads();
    for (int off = 1; off < 256; off <<= 1) {
        int u = (t >= off) ? s[t - off] : 0;
        __syncthreads();
        s[t] += u;
        __syncthreads();
    }
    if (idx < N_NODES) {
        int excl = blockOffs[blockIdx.x] + s[t] - v;
        rowstart[idx] = excl;
        cursor[idx]   = excl;
    }
}

__global__ void scatter_kernel(const int* __restrict__ src, const int* __restrict__ dst,
                               const float* __restrict__ val, int* __restrict__ cursor,
                               int2* __restrict__ edgeP) {
    int e = blockIdx.x * blockDim.x + threadIdx.x;
    if (e < N_EDGES) {
        int d   = dst[e];
        int pos = atomicAdd(&cursor[d], 1);
        edgeP[pos] = make_int2(src[e], __float_as_int(val[e]));
    }
}

// ---------------------------------------------------------------------------
// Propagation, bf16: thread t -> node i = t/12, octet q = t%12 (8 feats).
// h rows are 192B; 12 lanes x 16B (uint4 = 8 bf16) = one contiguous row.
// 8-edge unroll -> 8 independent 16B gathers in flight per lane.
// ---------------------------------------------------------------------------
__device__ __forceinline__ void acc8(float* a, float v, uint4 hv) {
    a[0] = fmaf(v, bflo(hv.x), a[0]); a[1] = fmaf(v, bfhi(hv.x), a[1]);
    a[2] = fmaf(v, bflo(hv.y), a[2]); a[3] = fmaf(v, bfhi(hv.y), a[3]);
    a[4] = fmaf(v, bflo(hv.z), a[4]); a[5] = fmaf(v, bfhi(hv.z), a[5]);
    a[6] = fmaf(v, bflo(hv.w), a[6]); a[7] = fmaf(v, bfhi(hv.w), a[7]);
}

template <bool FINAL>
__global__ __launch_bounds__(256) void prop_kernel(const ushort* __restrict__ h,
                                                   const ushort* __restrict__ sup,
                                                   const int* __restrict__ rowstart,
                                                   const int2* __restrict__ edgeP,
                                                   ushort* __restrict__ outB,
                                                   float* __restrict__ outF) {
    int t = blockIdx.x * 256 + threadIdx.x;
    int i = t / TPN;
    if (i >= N_NODES) return;
    int q = t - i * TPN;
    int f = q * 8;

    int start = rowstart[i];
    int end   = rowstart[i + 1];

    float a[8] = {0.f, 0.f, 0.f, 0.f, 0.f, 0.f, 0.f, 0.f};
    int e = start;
    for (; e + 7 < end; e += 8) {
        int2 ed[8];
        #pragma unroll
        for (int u = 0; u < 8; ++u) ed[u] = edgeP[e + u];
        uint4 hv[8];
        #pragma unroll
        for (int u = 0; u < 8; ++u)
            hv[u] = *(const uint4*)(h + (size_t)ed[u].x * OUT_F + f);
        #pragma unroll
        for (int u = 0; u < 8; ++u) acc8(a, __int_as_float(ed[u].y), hv[u]);
    }
    for (; e < end; ++e) {
        int2 e0 = edgeP[e];
        uint4 h0 = *(const uint4*)(h + (size_t)e0.x * OUT_F + f);
        acc8(a, __int_as_float(e0.y), h0);
    }

    size_t o = (size_t)i * OUT_F + f;
    uint4 sp = *(const uint4*)(sup + o);
    float r[8];
    r[0] = fmaxf(fmaf(a[0], 0.9f, bflo(sp.x) * 0.1f), 0.f);
    r[1] = fmaxf(fmaf(a[1], 0.9f, bfhi(sp.x) * 0.1f), 0.f);
    r[2] = fmaxf(fmaf(a[2], 0.9f, bflo(sp.y) * 0.1f), 0.f);
    r[3] = fmaxf(fmaf(a[3], 0.9f, bfhi(sp.y) * 0.1f), 0.f);
    r[4] = fmaxf(fmaf(a[4], 0.9f, bflo(sp.z) * 0.1f), 0.f);
    r[5] = fmaxf(fmaf(a[5], 0.9f, bfhi(sp.z) * 0.1f), 0.f);
    r[6] = fmaxf(fmaf(a[6], 0.9f, bflo(sp.w) * 0.1f), 0.f);
    r[7] = fmaxf(fmaf(a[7], 0.9f, bfhi(sp.w) * 0.1f), 0.f);

    if (FINAL) {
        *(float4*)(outF + o)     = make_float4(r[0], r[1], r[2], r[3]);
        *(float4*)(outF + o + 4) = make_float4(r[4], r[5], r[6], r[7]);
    } else {
        *(uint4*)(outB + o) = make_uint4(pack2bf(r[0], r[1]), pack2bf(r[2], r[3]),
                                         pack2bf(r[4], r[5]), pack2bf(r[6], r[7]));
    }
}

// ---------------------------------------------------------------------------
// Buffers: d_out low 9.6MB = supB (gemm out), top 98KB = wTp; final prop
// overwrites d_out fully (supB/wTp dead — props read the supP copy).
// d_in[0] (x, 102.4MB) = scratch AFTER gemm (sole reader of x). d_ws unused.
// Harness restores d_in before every launch.
// ---------------------------------------------------------------------------
extern "C" void kernel_launch(void* const* d_in, const int* in_sizes, int n_in,
                              void* d_out, int out_size, void* d_ws, size_t ws_size,
                              hipStream_t stream) {
    const float* x    = (const float*)d_in[0];
    const float* w    = (const float*)d_in[1];
    const int*   esrc = (const int*)d_in[2];
    const int*   edst = (const int*)d_in[3];
    const float* eval = (const float*)d_in[4];
    float* out = (float*)d_out;

    const size_t supBytes = (size_t)N_NODES * OUT_F * sizeof(ushort);  // 9.6MB
    ushort* supB = (ushort*)d_out;
    ushort* wTp  = (ushort*)((char*)d_out + (size_t)out_size * 4
                             - (size_t)IN_F * OUT_F * sizeof(ushort));

    char*  xb  = (char*)d_in[0];
    size_t off = 0;
    auto alloc = [&](size_t bytes) -> char* {
        char* p = xb + off;
        off = (off + bytes + 255) & ~(size_t)255;
        return p;
    };
    ushort* supP      = (ushort*)alloc(supBytes);                      // 9.6MB
    ushort* hU        = (ushort*)alloc(supBytes);                      // 9.6MB
    ushort* hV        = (ushort*)alloc(supBytes);                      // 9.6MB
    int2*   edgeP     = (int2*)alloc((size_t)N_EDGES * sizeof(int2));  // 6.4MB
    int*    rowstart  = (int*)alloc((N_NODES + 1) * sizeof(int));
    int*    cursor    = (int*)alloc(N_NODES * sizeof(int));
    int*    counts    = (int*)alloc(N_NODES * sizeof(int));
    int*    blockSums = (int*)alloc(SCAN_BLOCKS * sizeof(int));
    int*    blockOffs = (int*)alloc(SCAN_BLOCKS * sizeof(int));
    // ~36MB << 102.4MB

    // 1) weights -> bf16 chunk-major (d_out top)
    wt_kernel<<<(IN_F * OUT_F + 255) / 256, 256, 0, stream>>>(w, wTp);

    // 2) MFMA GEMM (last reader of x) -> supB in d_out
    gemm_kernel<<<(N_NODES + 63) / 64, 256, 0, stream>>>(x, wTp, supB);

    // 3) copy supB into x-scratch so final prop can freely write d_out
    hipMemcpyAsync(supP, supB, supBytes, hipMemcpyDeviceToDevice, stream);

    // 4) CSR build (x-scratch; safe post-gemm in stream order)
    zero_kernel<<<(N_NODES + 255) / 256, 256, 0, stream>>>(counts, N_NODES);
    hist_kernel<<<(N_EDGES + 255) / 256, 256, 0, stream>>>(edst, counts);
    block_reduce_kernel<<<SCAN_BLOCKS, 256, 0, stream>>>(counts, blockSums);
    scan_sums_kernel<<<1, 256, 0, stream>>>(blockSums, blockOffs, rowstart);
    block_scan_kernel<<<SCAN_BLOCKS, 256, 0, stream>>>(counts, blockOffs,
                                                       rowstart, cursor);
    scatter_kernel<<<(N_EDGES + 255) / 256, 256, 0, stream>>>(esrc, edst, eval,
                                                              cursor, edgeP);

    // 5) 10 propagation iterations: supP -> hU -> hV -> ... -> d_out (fp32)
    const int pgrid = (N_NODES * TPN + 255) / 256;
    const ushort* in = supP;
    for (int it = 1; it <= 9; ++it) {
        ushort* o = (it & 1) ? hU : hV;
        prop_kernel<false><<<pgrid, 256, 0, stream>>>(in, supP, rowstart, edgeP,
                                                      o, nullptr);
        in = o;
    }
    prop_kernel<true><<<pgrid, 256, 0, stream>>>(in, supP, rowstart, edgeP,
                                                 nullptr, out);
}

// Round 8
// 556.101 us; speedup vs baseline: 1.5171x; 1.0238x over previous
//
#include <hip/hip_runtime.h>

typedef unsigned int   uint;
typedef unsigned short ushort;
typedef __attribute__((ext_vector_type(8))) short bf16x8;   // 8 bf16 (4 VGPRs)
typedef __attribute__((ext_vector_type(4))) float f32x4;

#define N_NODES 50000
#define N_EDGES 800000
#define IN_F    512
#define OUT_F   96
#define SCAN_BLOCKS 196   // 196*256 >= 50000
#define TPN 12            // threads per node in prop (96 feats / 8 per lane)

// bf16 helpers (storage-only bf16; math in fp32)
__device__ __forceinline__ float bflo(uint u) { return __uint_as_float(u << 16); }
__device__ __forceinline__ float bfhi(uint u) { return __uint_as_float(u & 0xffff0000u); }
__device__ __forceinline__ uint f2bf(float x) {          // round-to-nearest-even
    uint u = __float_as_uint(x);
    return (u + 0x7fffu + ((u >> 16) & 1u)) >> 16;
}
__device__ __forceinline__ uint pack2bf(float lo, float hi) {
    return f2bf(lo) | (f2bf(hi) << 16);
}

// ---------------------------------------------------------------------------
// w[512,96] fp32 -> wTp chunk-major bf16: wTp[k/32][c][k%32].
// ---------------------------------------------------------------------------
__global__ __launch_bounds__(256) void wt_kernel(const float* __restrict__ w,
                                                 ushort* __restrict__ wTp) {
    int t = blockIdx.x * 256 + threadIdx.x;
    if (t < IN_F * OUT_F) {
        int k = t / OUT_F, c = t - k * OUT_F;
        wTp[(size_t)(k >> 5) * (OUT_F * 32) + c * 32 + (k & 31)] =
            (ushort)f2bf(w[t]);
    }
}

// ---------------------------------------------------------------------------
// MFMA GEMM: supB[N,96](bf16) = x[N,512] @ w[512,96]
// 64-thread blocks (1 wave, 16 rows) -> grid 3125 = 12.2 blocks/CU (small
// tail). x prefetched 2 chunks deep (64B/lane in flight vs ~900cy HBM lat);
// w prefetched 1 deep (L2-hot). 6x mfma_16x16x32_bf16 per 32-K chunk.
// ---------------------------------------------------------------------------
__global__ __launch_bounds__(64) void gemm_kernel(const float* __restrict__ x,
                                                  const ushort* __restrict__ wTp,
                                                  ushort* __restrict__ supB) {
    const int lane = threadIdx.x;
    const int m    = lane & 15;
    const int quad = lane >> 4;

    const int row  = blockIdx.x * 16 + m;
    const int arow = (row < N_NODES) ? row : (N_NODES - 1);
    const float*  xp = x + (size_t)arow * IN_F + quad * 8;
    const ushort* wp = wTp + (size_t)m * 32 + quad * 8;   // chunk 0 base

    f32x4 acc[6];
    #pragma unroll
    for (int ct = 0; ct < 6; ++ct) acc[ct] = (f32x4){0.f, 0.f, 0.f, 0.f};

    // prologue: x chunks 0,1 and w chunk 0 in flight
    float4 xA0 = *(const float4*)(xp);
    float4 xB0 = *(const float4*)(xp + 4);
    float4 xA1 = *(const float4*)(xp + 32);
    float4 xB1 = *(const float4*)(xp + 36);
    bf16x8 b[6];
    #pragma unroll
    for (int ct = 0; ct < 6; ++ct)
        b[ct] = *(const bf16x8*)(wp + ct * (16 * 32));

    #pragma unroll
    for (int it = 0; it < 16; ++it) {
        float4 nxa, nxb;
        bf16x8 nb[6];
        if (it + 2 < 16) {
            nxa = *(const float4*)(xp + (it + 2) * 32);
            nxb = *(const float4*)(xp + (it + 2) * 32 + 4);
        }
        if (it + 1 < 16) {
            const ushort* wpn = wp + (size_t)(it + 1) * (OUT_F * 32);
            #pragma unroll
            for (int ct = 0; ct < 6; ++ct)
                nb[ct] = *(const bf16x8*)(wpn + ct * (16 * 32));
        }
        union { uint u[4]; bf16x8 v; } af;
        af.u[0] = pack2bf(xA0.x, xA0.y); af.u[1] = pack2bf(xA0.z, xA0.w);
        af.u[2] = pack2bf(xB0.x, xB0.y); af.u[3] = pack2bf(xB0.z, xB0.w);
        #pragma unroll
        for (int ct = 0; ct < 6; ++ct)
            acc[ct] = __builtin_amdgcn_mfma_f32_16x16x32_bf16(af.v, b[ct],
                                                              acc[ct], 0, 0, 0);
        xA0 = xA1; xB0 = xB1; xA1 = nxa; xB1 = nxb;
        #pragma unroll
        for (int ct = 0; ct < 6; ++ct) b[ct] = nb[ct];
    }

    // C/D layout: col = lane&15 (=m), row = quad*4 + reg
    const int orow0 = blockIdx.x * 16 + quad * 4;
    #pragma unroll
    for (int ct = 0; ct < 6; ++ct) {
        #pragma unroll
        for (int r = 0; r < 4; ++r) {
            int gr = orow0 + r;
            if (gr < N_NODES)
                supB[(size_t)gr * OUT_F + ct * 16 + m] = (ushort)f2bf(acc[ct][r]);
        }
    }
}

// ---------------------------------------------------------------------------
// CSR build: histogram -> hierarchical scan -> scatter (4B packed edges:
// low 16 bits = src node id (50000 < 65536), high 16 bits = bf16 edge val)
// ---------------------------------------------------------------------------
__global__ void zero_kernel(int* __restrict__ p, int n) {
    int t = blockIdx.x * blockDim.x + threadIdx.x;
    if (t < n) p[t] = 0;
}

__global__ void hist_kernel(const int* __restrict__ dst, int* __restrict__ counts) {
    int e = blockIdx.x * blockDim.x + threadIdx.x;
    if (e < N_EDGES) atomicAdd(&counts[dst[e]], 1);
}

__global__ __launch_bounds__(256) void block_reduce_kernel(const int* __restrict__ counts,
                                                           int* __restrict__ blockSums) {
    __shared__ int s[256];
    int idx = blockIdx.x * 256 + threadIdx.x;
    s[threadIdx.x] = (idx < N_NODES) ? counts[idx] : 0;
    __syncthreads();
    for (int off = 128; off > 0; off >>= 1) {
        if (threadIdx.x < off) s[threadIdx.x] += s[threadIdx.x + off];
        __syncthreads();
    }
    if (threadIdx.x == 0) blockSums[blockIdx.x] = s[0];
}

__global__ __launch_bounds__(256) void scan_sums_kernel(int* __restrict__ blockSums,
                                                        int* __restrict__ blockOffs,
                                                        int* __restrict__ rowstart) {
    __shared__ int s[256];
    int t = threadIdx.x;
    s[t] = (t < SCAN_BLOCKS) ? blockSums[t] : 0;
    __syncthreads();
    for (int off = 1; off < 256; off <<= 1) {
        int v = (t >= off) ? s[t - off] : 0;
        __syncthreads();
        s[t] += v;
        __syncthreads();
    }
    if (t < SCAN_BLOCKS) blockOffs[t] = (t == 0) ? 0 : s[t - 1];
    if (t == 0) rowstart[N_NODES] = s[SCAN_BLOCKS - 1];
}

__global__ __launch_bounds__(256) void block_scan_kernel(const int* __restrict__ counts,
                                                         const int* __restrict__ blockOffs,
                                                         int* __restrict__ rowstart,
                                                         int* __restrict__ cursor) {
    __shared__ int s[256];
    int t   = threadIdx.x;
    int idx = blockIdx.x * 256 + t;
    int v   = (idx < N_NODES) ? counts[idx] : 0;
    s[t] = v;
    __syncthreads();
    for (int off = 1; off < 256; off <<= 1) {
        int u = (t >= off) ? s[t - off] : 0;
        __syncthreads();
        s[t] += u;
        __syncthreads();
    }
    if (idx < N_NODES) {
        int excl = blockOffs[blockIdx.x] + s[t] - v;
        rowstart[idx] = excl;
        cursor[idx]   = excl;
    }
}

__global__ void scatter_kernel(const int* __restrict__ src, const int* __restrict__ dst,
                               const float* __restrict__ val, int* __restrict__ cursor,
                               uint* __restrict__ edgeE) {
    int e = blockIdx.x * blockDim.x + threadIdx.x;
    if (e < N_EDGES) {
        int d   = dst[e];
        int pos = atomicAdd(&cursor[d], 1);
        edgeE[pos] = (f2bf(val[e]) << 16) | (uint)src[e];
    }
}

// ---------------------------------------------------------------------------
// Propagation, bf16: thread t -> node i = t/12, octet q = t%12 (8 feats).
// 4B edge records; 8-edge unroll -> 8 independent 16B gathers in flight.
// ---------------------------------------------------------------------------
__device__ __forceinline__ void acc8(float* a, float v, uint4 hv) {
    a[0] = fmaf(v, bflo(hv.x), a[0]); a[1] = fmaf(v, bfhi(hv.x), a[1]);
    a[2] = fmaf(v, bflo(hv.y), a[2]); a[3] = fmaf(v, bfhi(hv.y), a[3]);
    a[4] = fmaf(v, bflo(hv.z), a[4]); a[5] = fmaf(v, bfhi(hv.z), a[5]);
    a[6] = fmaf(v, bflo(hv.w), a[6]); a[7] = fmaf(v, bfhi(hv.w), a[7]);
}

template <bool FINAL>
__global__ __launch_bounds__(256) void prop_kernel(const ushort* __restrict__ h,
                                                   const ushort* __restrict__ sup,
                                                   const int* __restrict__ rowstart,
                                                   const uint* __restrict__ edgeE,
                                                   ushort* __restrict__ outB,
                                                   float* __restrict__ outF) {
    int t = blockIdx.x * 256 + threadIdx.x;
    int i = t / TPN;
    if (i >= N_NODES) return;
    int q = t - i * TPN;
    int f = q * 8;

    int start = rowstart[i];
    int end   = rowstart[i + 1];

    float a[8] = {0.f, 0.f, 0.f, 0.f, 0.f, 0.f, 0.f, 0.f};
    int e = start;
    for (; e + 7 < end; e += 8) {
        uint ed[8];
        #pragma unroll
        for (int u = 0; u < 8; ++u) ed[u] = edgeE[e + u];
        uint4 hv[8];
        #pragma unroll
        for (int u = 0; u < 8; ++u)
            hv[u] = *(const uint4*)(h + (size_t)(ed[u] & 0xffffu) * OUT_F + f);
        #pragma unroll
        for (int u = 0; u < 8; ++u) acc8(a, bfhi(ed[u]), hv[u]);
    }
    for (; e < end; ++e) {
        uint e0 = edgeE[e];
        uint4 h0 = *(const uint4*)(h + (size_t)(e0 & 0xffffu) * OUT_F + f);
        acc8(a, bfhi(e0), h0);
    }

    size_t o = (size_t)i * OUT_F + f;
    uint4 sp = *(const uint4*)(sup + o);
    float r[8];
    r[0] = fmaxf(fmaf(a[0], 0.9f, bflo(sp.x) * 0.1f), 0.f);
    r[1] = fmaxf(fmaf(a[1], 0.9f, bfhi(sp.x) * 0.1f), 0.f);
    r[2] = fmaxf(fmaf(a[2], 0.9f, bflo(sp.y) * 0.1f), 0.f);
    r[3] = fmaxf(fmaf(a[3], 0.9f, bfhi(sp.y) * 0.1f), 0.f);
    r[4] = fmaxf(fmaf(a[4], 0.9f, bflo(sp.z) * 0.1f), 0.f);
    r[5] = fmaxf(fmaf(a[5], 0.9f, bfhi(sp.z) * 0.1f), 0.f);
    r[6] = fmaxf(fmaf(a[6], 0.9f, bflo(sp.w) * 0.1f), 0.f);
    r[7] = fmaxf(fmaf(a[7], 0.9f, bfhi(sp.w) * 0.1f), 0.f);

    if (FINAL) {
        *(float4*)(outF + o)     = make_float4(r[0], r[1], r[2], r[3]);
        *(float4*)(outF + o + 4) = make_float4(r[4], r[5], r[6], r[7]);
    } else {
        *(uint4*)(outB + o) = make_uint4(pack2bf(r[0], r[1]), pack2bf(r[2], r[3]),
                                         pack2bf(r[4], r[5]), pack2bf(r[6], r[7]));
    }
}

// ---------------------------------------------------------------------------
// Buffers: d_out low 9.6MB = supB (gemm out), top 98KB = wTp; final prop
// overwrites d_out fully (supB/wTp dead — props read the supP copy).
// d_in[0] (x, 102.4MB) = scratch AFTER gemm (sole reader of x). d_ws unused.
// Harness restores d_in before every launch.
// ---------------------------------------------------------------------------
extern "C" void kernel_launch(void* const* d_in, const int* in_sizes, int n_in,
                              void* d_out, int out_size, void* d_ws, size_t ws_size,
                              hipStream_t stream) {
    const float* x    = (const float*)d_in[0];
    const float* w    = (const float*)d_in[1];
    const int*   esrc = (const int*)d_in[2];
    const int*   edst = (const int*)d_in[3];
    const float* eval = (const float*)d_in[4];
    float* out = (float*)d_out;

    const size_t supBytes = (size_t)N_NODES * OUT_F * sizeof(ushort);  // 9.6MB
    ushort* supB = (ushort*)d_out;
    ushort* wTp  = (ushort*)((char*)d_out + (size_t)out_size * 4
                             - (size_t)IN_F * OUT_F * sizeof(ushort));

    char*  xb  = (char*)d_in[0];
    size_t off = 0;
    auto alloc = [&](size_t bytes) -> char* {
        char* p = xb + off;
        off = (off + bytes + 255) & ~(size_t)255;
        return p;
    };
    ushort* supP      = (ushort*)alloc(supBytes);                      // 9.6MB
    ushort* hU        = (ushort*)alloc(supBytes);                      // 9.6MB
    ushort* hV        = (ushort*)alloc(supBytes);                      // 9.6MB
    uint*   edgeE     = (uint*)alloc((size_t)N_EDGES * sizeof(uint));  // 3.2MB
    int*    rowstart  = (int*)alloc((N_NODES + 1) * sizeof(int));
    int*    cursor    = (int*)alloc(N_NODES * sizeof(int));
    int*    counts    = (int*)alloc(N_NODES * sizeof(int));
    int*    blockSums = (int*)alloc(SCAN_BLOCKS * sizeof(int));
    int*    blockOffs = (int*)alloc(SCAN_BLOCKS * sizeof(int));
    // ~33MB << 102.4MB

    // 1) weights -> bf16 chunk-major (d_out top)
    wt_kernel<<<(IN_F * OUT_F + 255) / 256, 256, 0, stream>>>(w, wTp);

    // 2) MFMA GEMM (last reader of x) -> supB in d_out
    gemm_kernel<<<(N_NODES + 15) / 16, 64, 0, stream>>>(x, wTp, supB);

    // 3) copy supB into x-scratch so final prop can freely write d_out
    hipMemcpyAsync(supP, supB, supBytes, hipMemcpyDeviceToDevice, stream);

    // 4) CSR build (x-scratch; safe post-gemm in stream order)
    zero_kernel<<<(N_NODES + 255) / 256, 256, 0, stream>>>(counts, N_NODES);
    hist_kernel<<<(N_EDGES + 255) / 256, 256, 0, stream>>>(edst, counts);
    block_reduce_kernel<<<SCAN_BLOCKS, 256, 0, stream>>>(counts, blockSums);
    scan_sums_kernel<<<1, 256, 0, stream>>>(blockSums, blockOffs, rowstart);
    block_scan_kernel<<<SCAN_BLOCKS, 256, 0, stream>>>(counts, blockOffs,
                                                       rowstart, cursor);
    scatter_kernel<<<(N_EDGES + 255) / 256, 256, 0, stream>>>(esrc, edst, eval,
                                                              cursor, edgeE);

    // 5) 10 propagation iterations: supP -> hU -> hV -> ... -> d_out (fp32)
    const int pgrid = (N_NODES * TPN + 255) / 256;
    const ushort* in = supP;
    for (int it = 1; it <= 9; ++it) {
        ushort* o = (it & 1) ? hU : hV;
        prop_kernel<false><<<pgrid, 256, 0, stream>>>(in, supP, rowstart, edgeE,
                                                      o, nullptr);
        in = o;
    }
    prop_kernel<true><<<pgrid, 256, 0, stream>>>(in, supP, rowstart, edgeE,
                                                 nullptr, out);
}